// Round 1
// 790.237 us; speedup vs baseline: 1.0449x; 1.0449x over previous
//
#include <hip/hip_runtime.h>
#include <hip/hip_bf16.h>
#include <hip/hip_fp16.h>

// SimpleRNN: B=64, S=2048, IN=256, H=128, OUT=3 (all fp32)
// Phase 1 (r10): xproj = x @ W_xh^T + b_xh via f16 MFMA (fp32 accumulate).
//   Old fp32 VALU GEMM ran 244 us (4.4x its 55 us issue floor, MfmaUtil=0).
//   New: 128x128 tile/block, 4 waves (2x2 of 64x64), mfma_f32_16x16x32_f16,
//   convert-on-stage f32->f16 into 80-B-pitch LDS. Memory floor ~32 us.
// Phase 2: scan, byte-identical to r9 (581 us, latency-bound serial chain).

#define RNN_B   64
#define RNN_S   2048
#define RNN_IN  256
#define RNN_H   128
#define RNN_OUT 3

typedef _Float16 half2v __attribute__((ext_vector_type(2)));
typedef _Float16 half4 __attribute__((ext_vector_type(4)));
typedef _Float16 half8 __attribute__((ext_vector_type(8)));
typedef float f32x4 __attribute__((ext_vector_type(4)));

#if __has_builtin(__builtin_amdgcn_fdot2)
#define FDOT2(a, b, c) __builtin_amdgcn_fdot2((a), (b), (c), false)
#else
#define FDOT2(a, b, c) \
  fmaf((float)(a).x, (float)(b).x, fmaf((float)(a).y, (float)(b).y, (c)))
#endif

// h LDS layout (f16): slice q = k>>5 (32 halves = 64 B) stored at byte
// 80*q (pad 16 B per slice). Half-index: HPOSH(k) = 40*(k>>5) + (k&31).
#define HPOSH(k) (40 * ((k) >> 5) + ((k) & 31))

// ---------------------------------------------------------------------------
// Phase 1: f16 MFMA GEMM  C[M=131072, N=128] = A[M,256] * B[128,256]^T + bias
// Tile 128x128, K-chunk 32 (one MFMA K). 256 threads = 4 waves, each wave
// owns a 64x64 quadrant (4x4 fragments of 16x16, fp32 acc).
// LDS rows padded to 40 halves (80 B) -> 2-way bank aliasing only (free).
// Fragment layout (HW-verified ladder mapping):
//   A: row = lane&15, k = 8*(lane>>4)+j   (half8 = contiguous 16 B)
//   B: col = lane&15, k = 8*(lane>>4)+j
//   C/D: col = lane&15, row = 4*(lane>>4)+reg
// ---------------------------------------------------------------------------
__global__ __launch_bounds__(256) void xproj_mfma(
    const float* __restrict__ x, const float* __restrict__ Wxh,
    const float* __restrict__ bxh, float* __restrict__ xp) {
  __shared__ __align__(16) _Float16 Ash[128][40];
  __shared__ __align__(16) _Float16 Bsh[128][40];

  const int tid = threadIdx.x;
  const int m0 = blockIdx.x * 128;
  const int wv = tid >> 6;
  const int lane = tid & 63;
  const int wr = wv >> 1;          // wave row (0..1) -> M offset 64*wr
  const int wc = wv & 1;           // wave col (0..1) -> N offset 64*wc
  const int fr = lane & 15;        // fragment row/col index
  const int fk = lane >> 4;        // k-group 0..3

  // staging coords: one float4 per thread per pass, 4 passes cover 128 rows
  const int lr = tid >> 3;         // row 0..31 (+32*p)
  const int lc = (tid & 7) * 4;    // k-col 0..28 within 32-chunk

  f32x4 acc[4][4];
#pragma unroll
  for (int m = 0; m < 4; ++m)
#pragma unroll
    for (int n = 0; n < 4; ++n) {
      acc[m][n][0] = 0.f; acc[m][n][1] = 0.f;
      acc[m][n][2] = 0.f; acc[m][n][3] = 0.f;
    }

  for (int kc = 0; kc < RNN_IN; kc += 32) {
#pragma unroll
    for (int p = 0; p < 4; ++p) {
      const int row = lr + 32 * p;
      const float4 va = *(const float4*)&x[(size_t)(m0 + row) * RNN_IN + kc + lc];
      half4 ha;
      ha.x = (_Float16)va.x; ha.y = (_Float16)va.y;
      ha.z = (_Float16)va.z; ha.w = (_Float16)va.w;
      *(half4*)&Ash[row][lc] = ha;
      const float4 vb = *(const float4*)&Wxh[(size_t)row * RNN_IN + kc + lc];
      half4 hb;
      hb.x = (_Float16)vb.x; hb.y = (_Float16)vb.y;
      hb.z = (_Float16)vb.z; hb.w = (_Float16)vb.w;
      *(half4*)&Bsh[row][lc] = hb;
    }
    __syncthreads();

    half8 af[4], bf[4];
#pragma unroll
    for (int m = 0; m < 4; ++m)
      af[m] = *(const half8*)&Ash[wr * 64 + m * 16 + fr][fk * 8];
#pragma unroll
    for (int n = 0; n < 4; ++n)
      bf[n] = *(const half8*)&Bsh[wc * 64 + n * 16 + fr][fk * 8];
#pragma unroll
    for (int m = 0; m < 4; ++m)
#pragma unroll
      for (int n = 0; n < 4; ++n)
        acc[m][n] = __builtin_amdgcn_mfma_f32_16x16x32_f16(
            af[m], bf[n], acc[m][n], 0, 0, 0);
    __syncthreads();
  }

  // epilogue: bias + store (16-lane 64-B coalesced segments per store group)
  float bb[4];
#pragma unroll
  for (int n = 0; n < 4; ++n) bb[n] = bxh[wc * 64 + n * 16 + fr];
#pragma unroll
  for (int m = 0; m < 4; ++m) {
    const size_t rbase = (size_t)(m0 + wr * 64 + m * 16 + 4 * fk);
#pragma unroll
    for (int reg = 0; reg < 4; ++reg) {
      float* rowp = &xp[(rbase + reg) * RNN_H];
#pragma unroll
      for (int n = 0; n < 4; ++n)
        rowp[wc * 64 + n * 16 + fr] = acc[m][n][reg] + bb[n];
    }
  }
}

// fast tanh: 1 - 2/(exp(2x)+1); saturates correctly at +-inf
__device__ __forceinline__ float fast_tanh(float a) {
  const float e = __expf(2.f * a);
  return 1.f - 2.f / (e + 1.f);
}

// LDS-only barrier: does NOT drain vmcnt (HIP __syncthreads emits vmcnt(0)),
// so global prefetch loads stay in flight across the barrier.
__device__ __forceinline__ void block_sync_lds() {
  asm volatile("s_waitcnt lgkmcnt(0)" ::: "memory");
  __builtin_amdgcn_s_barrier();
}

// 4-lane (quad) sum via DPP quad_perm -- pure VALU (~4 cyc/op), replacing
// __shfl_xor's ds_bpermute (~65 cyc DS-crossbar latency each).
// 0xB1 = quad_perm [1,0,3,2] (xor 1); 0x4E = quad_perm [2,3,0,1] (xor 2).
__device__ __forceinline__ float quad_sum_dpp(float s) {
  int t = __builtin_amdgcn_mov_dpp(__builtin_bit_cast(int, s),
                                   0xB1, 0xF, 0xF, true);
  s += __builtin_bit_cast(float, t);
  t = __builtin_amdgcn_mov_dpp(__builtin_bit_cast(int, s),
                               0x4E, 0xF, 0xF, true);
  s += __builtin_bit_cast(float, t);
  return s;
}

// 16 named half2 weight registers per thread (32 f16 = quarter W_hh row).
#define RNN_W_LIST(M) \
  M(0)  M(1)  M(2)  M(3)  M(4)  M(5)  M(6)  M(7)  \
  M(8)  M(9)  M(10) M(11) M(12) M(13) M(14) M(15)

#define WDECL(i) half2v w##i;
#define WLOADH(i)                                   \
  {                                                 \
    half2v _t;                                      \
    _t.x = (_Float16)wr[2 * (i)];                   \
    _t.y = (_Float16)wr[2 * (i) + 1];               \
    w##i = _t;                                      \
  }

// One step: thread (row r, quarter q) reads its 32-half k-slice of old h
// from BIN (4 x ds_read_b128, conflict-free by 80-B slice stride), 16
// full-rate v_dot2_f32_f16 with fp32 accumulate, DPP quad reduction (VALU),
// tanh in fp32, q==0 lane writes f16 h[r] to BOUT, single LDS-only barrier.
// PREG consumed early then refilled with xp[TNEXT] (fp32; stays in flight
// ~4 steps; barrier never drains vmcnt).
#define RNN_STEP(BIN, BOUT, PREG, TNEXT)                              \
  {                                                                  \
    const float4* hq = (const float4*)(BIN) + 5 * q;                 \
    const float xin = PREG;                                          \
    PREG = xpb[(size_t)(TNEXT) * RNN_H + r];                         \
    union { float4 f4; half2v h[4]; } u0, u1, u2, u3;                \
    u0.f4 = hq[0]; u1.f4 = hq[1]; u2.f4 = hq[2]; u3.f4 = hq[3];      \
    float acc0 = 0.f, acc1 = 0.f, acc2 = 0.f, acc3 = 0.f;            \
    acc0 = FDOT2(w0,  u0.h[0], acc0);                                \
    acc1 = FDOT2(w1,  u0.h[1], acc1);                                \
    acc2 = FDOT2(w2,  u0.h[2], acc2);                                \
    acc3 = FDOT2(w3,  u0.h[3], acc3);                                \
    acc0 = FDOT2(w4,  u1.h[0], acc0);                                \
    acc1 = FDOT2(w5,  u1.h[1], acc1);                                \
    acc2 = FDOT2(w6,  u1.h[2], acc2);                                \
    acc3 = FDOT2(w7,  u1.h[3], acc3);                                \
    acc0 = FDOT2(w8,  u2.h[0], acc0);                                \
    acc1 = FDOT2(w9,  u2.h[1], acc1);                                \
    acc2 = FDOT2(w10, u2.h[2], acc2);                                \
    acc3 = FDOT2(w11, u2.h[3], acc3);                                \
    acc0 = FDOT2(w12, u3.h[0], acc0);                                \
    acc1 = FDOT2(w13, u3.h[1], acc1);                                \
    acc2 = FDOT2(w14, u3.h[2], acc2);                                \
    acc3 = FDOT2(w15, u3.h[3], acc3);                                \
    float s = (acc0 + acc1) + (acc2 + acc3);                         \
    s = quad_sum_dpp(s);                                             \
    const float hv = fast_tanh(bias + xin + s);                      \
    if (q == 0) ((_Float16*)(BOUT))[hw] = (_Float16)hv;              \
    block_sync_lds();                                                \
  }

// ---------------------------------------------------------------------------
// Phase 2: recurrence. grid=64 blocks, block=512 threads (8 waves).
// Aligned 4-lane group owns row r = 16*wave + (lane>>2); thread holds
// W_hh[r, 32q..32q+31] as 16 half2 regs (~36 VGPR working set, spill-free).
// h (f16) double-buffered in padded LDS; 1 barrier/step; 4-deep prefetch.
// ---------------------------------------------------------------------------
__global__ __launch_bounds__(512, 2) void rnn_scan(
    const float* __restrict__ xp, const float* __restrict__ Whh,
    const float* __restrict__ bhh, const float* __restrict__ bh,
    const float* __restrict__ Wfc, const float* __restrict__ bfc,
    float* __restrict__ out) {
  const int b = blockIdx.x;
  const int tid = threadIdx.x;        // 0..511
  const int wv = tid >> 6;            // wave 0..7
  const int lane = tid & 63;
  const int q = lane & 3;             // k-quarter (32 halves)
  const int r = wv * 16 + (lane >> 2);  // row 0..127

  // 4 slices x 80 B = 320 B per buffer, float4-typed for b128 access
  __shared__ float4 hsA[20];
  __shared__ float4 hsB[20];

  const float* wr = &Whh[(size_t)r * RNN_H + 32 * q];
  RNN_W_LIST(WDECL)
  RNN_W_LIST(WLOADH)

  const float bias = bhh[r] + bh[r];
  const int hw = HPOSH(r);            // f16 write slot for row r

  // zero both h buffers incl. pads (80 floats = 320 B each)
  if (tid < 80) ((float*)hsA)[tid] = 0.f;
  block_sync_lds();

  const float* xpb = xp + (size_t)b * RNN_S * RNN_H;

  // 4-deep fp32 prefetch, one register per unrolled body
  float p0 = xpb[0 * RNN_H + r];
  float p1 = xpb[1 * RNN_H + r];
  float p2 = xpb[2 * RNN_H + r];
  float p3 = xpb[3 * RNN_H + r];

#pragma unroll 1
  for (int t = 0; t < RNN_S; t += 4) {
    const int n0 = (t + 4 < RNN_S) ? t + 4 : RNN_S - 1;
    const int n1 = (t + 5 < RNN_S) ? t + 5 : RNN_S - 1;
    const int n2 = (t + 6 < RNN_S) ? t + 6 : RNN_S - 1;
    const int n3 = (t + 7 < RNN_S) ? t + 7 : RNN_S - 1;
    RNN_STEP(hsA, hsB, p0, n0)
    RNN_STEP(hsB, hsA, p1, n1)
    RNN_STEP(hsA, hsB, p2, n2)
    RNN_STEP(hsB, hsA, p3, n3)
  }
  // 2048 steps: last body writes hsA; trailing block_sync_lds made it visible.

  // fused FC: out[b][o] = sum_k hs[k] * Wfc[o][k] + bfc[o]
  if (tid < RNN_OUT) {
    float s = bfc[tid];
    const _Float16* hf = (const _Float16*)hsA;
#pragma unroll 4
    for (int k = 0; k < RNN_H; ++k)
      s = fmaf(Wfc[(size_t)tid * RNN_H + k], (float)hf[HPOSH(k)], s);
    out[b * RNN_OUT + tid] = s;
  }
}

extern "C" void kernel_launch(void* const* d_in, const int* in_sizes, int n_in,
                              void* d_out, int out_size, void* d_ws, size_t ws_size,
                              hipStream_t stream) {
  const float* x   = (const float*)d_in[0];
  const float* Wxh = (const float*)d_in[1];
  const float* bxh = (const float*)d_in[2];
  const float* Whh = (const float*)d_in[3];
  const float* bhh = (const float*)d_in[4];
  const float* bh  = (const float*)d_in[5];
  const float* Wfc = (const float*)d_in[6];
  const float* bfc = (const float*)d_in[7];
  float* out = (float*)d_out;
  float* xp  = (float*)d_ws;  // 131072*128*4 = 64 MiB

  xproj_mfma<<<dim3((RNN_B * RNN_S) / 128), dim3(256), 0, stream>>>(x, Wxh, bxh, xp);
  rnn_scan<<<dim3(RNN_B), dim3(512), 0, stream>>>(xp, Whh, bhh, bh, Wfc, bfc, out);
}